// Round 1
// baseline (142.683 us; speedup 1.0000x reference)
//
#include <hip/hip_runtime.h>

// Problem constants (compile-time)
#define BB   16
#define CIN  64
#define NF   257
#define NT   512
#define T4   (NT/4)          // 128 float4 per row
#define FT4  (NF*T4)         // 32896 float4 per channel plane

__device__ __forceinline__ float4 f4(float v) { return make_float4(v, v, v, v); }

__device__ __forceinline__ void fma4(float4& a, float w, const float4& x) {
    a.x = fmaf(w, x.x, a.x); a.y = fmaf(w, x.y, a.y);
    a.z = fmaf(w, x.z, a.z); a.w = fmaf(w, x.w, a.w);
}
__device__ __forceinline__ float4 relu4(float4 a) {
    return make_float4(fmaxf(a.x, 0.f), fmaxf(a.y, 0.f), fmaxf(a.z, 0.f), fmaxf(a.w, 0.f));
}
__device__ __forceinline__ float ssign1(float x) { return x / (1.f + fabsf(x)); }
__device__ __forceinline__ float4 ssign4(float4 a) {
    return make_float4(ssign1(a.x), ssign1(a.y), ssign1(a.z), ssign1(a.w));
}
__device__ __forceinline__ float sigm1(float x) { return 1.f / (1.f + __expf(-x)); }
__device__ __forceinline__ float4 sigm4(float4 a) {
    return make_float4(sigm1(a.x), sigm1(a.y), sigm1(a.z), sigm1(a.w));
}
__device__ __forceinline__ float4 mul4(float4 a, float4 b) {
    return make_float4(a.x * b.x, a.y * b.y, a.z * b.z, a.w * b.w);
}
__device__ __forceinline__ float4 fma44(float4 a, float4 b, float4 c) {
    return make_float4(fmaf(a.x, b.x, c.x), fmaf(a.y, b.y, c.y),
                       fmaf(a.z, b.z, c.z), fmaf(a.w, b.w, c.w));
}

__global__ __launch_bounds__(256) void outconv_fused(
    const float* __restrict__ xdec,   // [B,64,F,T]
    const float* __restrict__ xskip,  // [B,4,F,T]
    const float* __restrict__ W1,     // [11,64]
    const float* __restrict__ b1,     // [11]
    const float* __restrict__ W2,     // [11,15]
    const float* __restrict__ b2,     // [11]
    float* __restrict__ out)          // [B,4,F,T]
{
    // Weights transposed into LDS: sW14[c*3 + j] holds W1[4j..4j+3][c] (row 11 padded 0)
    __shared__ float4 sW14[CIN * 3];
    __shared__ float4 sW24[15 * 3];
    __shared__ float  sB1[12];
    __shared__ float  sB2[12];

    {
        float* s = (float*)sW14;
        for (int i = threadIdx.x; i < CIN * 12; i += 256) {
            int c = i / 12, o = i - c * 12;
            s[i] = (o < 11) ? W1[o * CIN + c] : 0.f;
        }
        float* s2 = (float*)sW24;
        for (int i = threadIdx.x; i < 15 * 12; i += 256) {
            int c = i / 12, o = i - c * 12;
            s2[i] = (o < 11) ? W2[o * 15 + c] : 0.f;
        }
        if (threadIdx.x < 12) {
            int o = threadIdx.x;
            sB1[o] = (o < 11) ? b1[o] : 0.f;
            sB2[o] = (o < 11) ? b2[o] : 0.f;
        }
    }
    __syncthreads();

    const int v  = blockIdx.x * 256 + threadIdx.x;  // float4-pixel index
    const int t4 = v & (T4 - 1);
    const int bf = v >> 7;          // b*NF + f
    const int f  = bf % NF;
    const int b  = bf / NF;

    const float4* xd4 = (const float4*)xdec  + (size_t)b * CIN * FT4 + (size_t)f * T4 + t4;
    const float4* xs4 = (const float4*)xskip + (size_t)b * 4   * FT4 + (size_t)f * T4 + t4;
    float4*       o4  = (float4*)out         + (size_t)b * 4   * FT4 + (size_t)f * T4 + t4;

    // Skip channels (issued early; consumed at the end)
    float4 s0 = xs4[0];
    float4 s1 = xs4[FT4];
    float4 s2 = xs4[2 * FT4];
    float4 s3 = xs4[3 * FT4];

    // conv1: h[o] = relu(b1[o] + sum_c W1[o,c] * xd[c])
    float4 h[11];
    #pragma unroll
    for (int o = 0; o < 11; ++o) h[o] = f4(sB1[o]);

    #pragma unroll 8
    for (int c = 0; c < CIN; ++c) {
        float4 x  = xd4[(size_t)c * FT4];
        float4 wA = sW14[c * 3 + 0];
        float4 wB = sW14[c * 3 + 1];
        float4 wC = sW14[c * 3 + 2];
        fma4(h[0], wA.x, x); fma4(h[1], wA.y, x); fma4(h[2],  wA.z, x); fma4(h[3], wA.w, x);
        fma4(h[4], wB.x, x); fma4(h[5], wB.y, x); fma4(h[6],  wB.z, x); fma4(h[7], wB.w, x);
        fma4(h[8], wC.x, x); fma4(h[9], wC.y, x); fma4(h[10], wC.z, x);
    }
    #pragma unroll
    for (int o = 0; o < 11; ++o) h[o] = relu4(h[o]);

    // conv2: out[o] = b2[o] + sum_{c<4} W2[o,c]*skip[c] + sum_j W2[o,4+j]*h[j]
    float4 o2[11];
    #pragma unroll
    for (int o = 0; o < 11; ++o) o2[o] = f4(sB2[o]);

#define W2COL(cidx, xvec)                                                         \
    {                                                                             \
        float4 wA = sW24[(cidx) * 3 + 0];                                         \
        float4 wB = sW24[(cidx) * 3 + 1];                                         \
        float4 wC = sW24[(cidx) * 3 + 2];                                         \
        fma4(o2[0], wA.x, xvec); fma4(o2[1], wA.y, xvec);                         \
        fma4(o2[2], wA.z, xvec); fma4(o2[3], wA.w, xvec);                         \
        fma4(o2[4], wB.x, xvec); fma4(o2[5], wB.y, xvec);                         \
        fma4(o2[6], wB.z, xvec); fma4(o2[7], wB.w, xvec);                         \
        fma4(o2[8], wC.x, xvec); fma4(o2[9], wC.y, xvec);                         \
        fma4(o2[10], wC.z, xvec);                                                 \
    }

    W2COL(0, s0)
    W2COL(1, s1)
    W2COL(2, s2)
    W2COL(3, s3)
    #pragma unroll
    for (int j = 0; j < 11; ++j) W2COL(4 + j, h[j])
#undef W2COL

    // activations + grouped contraction
    float4 m0 = sigm4(o2[9]);
    float4 m1 = sigm4(o2[10]);

    float4 y0 = mul4(m0, fma44(ssign4(o2[0]), s0, fma44(ssign4(o2[1]), s1, mul4(ssign4(o2[2]), s2))));
    float4 y1 = mul4(m0, fma44(ssign4(o2[3]), s0, fma44(ssign4(o2[4]), s1, mul4(ssign4(o2[5]), s2))));
    float4 y2 = mul4(m0, fma44(ssign4(o2[6]), s0, fma44(ssign4(o2[7]), s1, mul4(ssign4(o2[8]), s2))));
    float4 y3 = mul4(m1, s3);

    o4[0]       = y0;
    o4[FT4]     = y1;
    o4[2 * FT4] = y2;
    o4[3 * FT4] = y3;
}

extern "C" void kernel_launch(void* const* d_in, const int* in_sizes, int n_in,
                              void* d_out, int out_size, void* d_ws, size_t ws_size,
                              hipStream_t stream) {
    const float* xdec  = (const float*)d_in[0];
    const float* xskip = (const float*)d_in[1];
    const float* W1    = (const float*)d_in[2];
    const float* b1    = (const float*)d_in[3];
    const float* W2    = (const float*)d_in[4];
    const float* b2    = (const float*)d_in[5];
    float* outp = (float*)d_out;

    const int total_v = BB * NF * T4;      // 526336
    const int blocks  = total_v / 256;     // 2056 exact
    outconv_fused<<<blocks, 256, 0, stream>>>(xdec, xskip, W1, b1, W2, b2, outp);
}